// Round 1
// baseline (378.025 us; speedup 1.0000x reference)
//
#include <hip/hip_runtime.h>
#include <math.h>

#define ROWS 512       // B*S = B*T
#define DMODEL 256
#define NH 8
#define DH 32
#define NEG_INF -1e30f

// ---------------- LayerNorm over src (ln1) and tgt (lnt) ----------------
__global__ __launch_bounds__(64) void ln_qt_kernel(
    const float* __restrict__ src, const float* __restrict__ tgt,
    const float* __restrict__ g1, const float* __restrict__ b1,
    const float* __restrict__ gt, const float* __restrict__ bt,
    float* __restrict__ S2, float* __restrict__ TNb)
{
  int row = blockIdx.x;           // 0..1023
  const float* x; float* o; const float* g; const float* b;
  if (row < ROWS) { x = src + row * DMODEL; o = S2 + row * DMODEL; g = g1; b = b1; }
  else { int r = row - ROWS; x = tgt + r * DMODEL; o = TNb + r * DMODEL; g = gt; b = bt; }
  int lane = threadIdx.x;
  float4 v = ((const float4*)x)[lane];
  float s  = v.x + v.y + v.z + v.w;
  float ss = v.x*v.x + v.y*v.y + v.z*v.z + v.w*v.w;
#pragma unroll
  for (int off = 32; off >= 1; off >>= 1) {
    s  += __shfl_xor(s,  off);
    ss += __shfl_xor(ss, off);
  }
  float mean = s * (1.0f / 256.0f);
  float var  = ss * (1.0f / 256.0f) - mean * mean;
  float rstd = rsqrtf(var + 1e-5f);
  float4 gg = ((const float4*)g)[lane];
  float4 bb = ((const float4*)b)[lane];
  float4 ov;
  ov.x = (v.x - mean) * rstd * gg.x + bb.x;
  ov.y = (v.y - mean) * rstd * gg.y + bb.y;
  ov.z = (v.z - mean) * rstd * gg.z + bb.z;
  ov.w = (v.w - mean) * rstd * gg.w + bb.w;
  ((float4*)o)[lane] = ov;
}

// ---------------- LN2 + FF2-output init (residual + b2, masked) ----------------
__global__ __launch_bounds__(64) void ln2_kernel(
    const float* __restrict__ X, const float* __restrict__ g, const float* __restrict__ b,
    const float* __restrict__ b2, const int* __restrict__ smask,
    float* __restrict__ XN, float* __restrict__ outinit)
{
  int row = blockIdx.x;           // 0..511
  int lane = threadIdx.x;
  float4 v = ((const float4*)(X + row * DMODEL))[lane];
  float s  = v.x + v.y + v.z + v.w;
  float ss = v.x*v.x + v.y*v.y + v.z*v.z + v.w*v.w;
#pragma unroll
  for (int off = 32; off >= 1; off >>= 1) {
    s  += __shfl_xor(s,  off);
    ss += __shfl_xor(ss, off);
  }
  float mean = s * (1.0f / 256.0f);
  float var  = ss * (1.0f / 256.0f) - mean * mean;
  float rstd = rsqrtf(var + 1e-5f);
  float4 gg = ((const float4*)g)[lane];
  float4 bb = ((const float4*)b)[lane];
  float4 ov;
  ov.x = (v.x - mean) * rstd * gg.x + bb.x;
  ov.y = (v.y - mean) * rstd * gg.y + bb.y;
  ov.z = (v.z - mean) * rstd * gg.z + bb.z;
  ov.w = (v.w - mean) * rstd * gg.w + bb.w;
  ((float4*)(XN + row * DMODEL))[lane] = ov;
  float mm = (smask[row] != 0) ? 0.0f : 1.0f;
  float4 b2v = ((const float4*)b2)[lane];
  float4 oi;
  oi.x = mm * (v.x + b2v.x);
  oi.y = mm * (v.y + b2v.y);
  oi.z = mm * (v.z + b2v.z);
  oi.w = mm * (v.w + b2v.w);
  ((float4*)(outinit + row * DMODEL))[lane] = oi;
}

// ---------------- shared GEMM core: 64x64 tile, 4x4 micro, KC=32 ----------------
__device__ __forceinline__ void gemm_core(
    const float* __restrict__ A, int lda,
    const float* __restrict__ Bw, int ldb,
    int kbeg, int kend, int m0, int n0,
    float acc[4][4])
{
  __shared__ float At[32][68];   // [k][row], pad 68: ty-stride 4 banks -> 2-way max
  __shared__ float Bs[32][64];
  int tid = threadIdx.x;
  int tx = tid & 15, ty = tid >> 4;
  int ar = tid & 63;             // A row within tile
  int ak = (tid >> 6) * 8;       // A k-chunk
  int bk = tid >> 4;             // B row 0..15 (and +16)
  int bc = (tid & 15) * 4;       // B col
  for (int kc = kbeg; kc < kend; kc += 32) {
    const float* ap = A + (size_t)(m0 + ar) * lda + kc + ak;
    float4 a0 = *(const float4*)ap;
    float4 a1 = *(const float4*)(ap + 4);
    const float* bp = Bw + (size_t)(kc + bk) * ldb + n0 + bc;
    float4 b0  = *(const float4*)bp;
    float4 b1v = *(const float4*)(bp + 16 * ldb);
    At[ak+0][ar] = a0.x; At[ak+1][ar] = a0.y; At[ak+2][ar] = a0.z; At[ak+3][ar] = a0.w;
    At[ak+4][ar] = a1.x; At[ak+5][ar] = a1.y; At[ak+6][ar] = a1.z; At[ak+7][ar] = a1.w;
    *(float4*)&Bs[bk][bc]      = b0;
    *(float4*)&Bs[bk+16][bc]   = b1v;
    __syncthreads();
#pragma unroll
    for (int k = 0; k < 32; ++k) {
      float4 av = *(const float4*)&At[k][ty * 4];
      float4 bv = *(const float4*)&Bs[k][tx * 4];
      acc[0][0] = fmaf(av.x, bv.x, acc[0][0]); acc[0][1] = fmaf(av.x, bv.y, acc[0][1]);
      acc[0][2] = fmaf(av.x, bv.z, acc[0][2]); acc[0][3] = fmaf(av.x, bv.w, acc[0][3]);
      acc[1][0] = fmaf(av.y, bv.x, acc[1][0]); acc[1][1] = fmaf(av.y, bv.y, acc[1][1]);
      acc[1][2] = fmaf(av.y, bv.z, acc[1][2]); acc[1][3] = fmaf(av.y, bv.w, acc[1][3]);
      acc[2][0] = fmaf(av.z, bv.x, acc[2][0]); acc[2][1] = fmaf(av.z, bv.y, acc[2][1]);
      acc[2][2] = fmaf(av.z, bv.z, acc[2][2]); acc[2][3] = fmaf(av.z, bv.w, acc[2][3]);
      acc[3][0] = fmaf(av.w, bv.x, acc[3][0]); acc[3][1] = fmaf(av.w, bv.y, acc[3][1]);
      acc[3][2] = fmaf(av.w, bv.z, acc[3][2]); acc[3][3] = fmaf(av.w, bv.w, acc[3][3]);
    }
    __syncthreads();
  }
}

// ---------------- QKV: grid (4,8,3); Q prescaled; K/V stored [B,H,T,Dh] ----------------
__global__ __launch_bounds__(256) void qkv_kernel(
    const float* __restrict__ S2, const float* __restrict__ TNb,
    const float* __restrict__ wq, const float* __restrict__ wk, const float* __restrict__ wv,
    const float* __restrict__ bq, const float* __restrict__ bk, const float* __restrict__ bv,
    float* __restrict__ Qb, float* __restrict__ Kb, float* __restrict__ Vb)
{
  int z = blockIdx.z;
  const float* A    = (z == 0) ? S2 : TNb;
  const float* Bw   = (z == 0) ? wq : (z == 1) ? wk : wv;
  const float* bias = (z == 0) ? bq : (z == 1) ? bk : bv;
  int m0 = blockIdx.y * 64, n0 = blockIdx.x * 64;
  float acc[4][4] = {};
  gemm_core(A, DMODEL, Bw, DMODEL, 0, DMODEL, m0, n0, acc);
  int tid = threadIdx.x, tx = tid & 15, ty = tid >> 4;
  int c0 = n0 + tx * 4;
  const float scale = 0.1767766952966369f; // 1/sqrt(32)
#pragma unroll
  for (int i = 0; i < 4; ++i) {
    int m = m0 + ty * 4 + i;
    float4 r;
    r.x = acc[i][0] + bias[c0 + 0];
    r.y = acc[i][1] + bias[c0 + 1];
    r.z = acc[i][2] + bias[c0 + 2];
    r.w = acc[i][3] + bias[c0 + 3];
    if (z == 0) {
      r.x *= scale; r.y *= scale; r.z *= scale; r.w *= scale;
      *(float4*)&Qb[m * DMODEL + c0] = r;
    } else {
      int b = m >> 8, t = m & 255, h = c0 >> 5, d0 = c0 & 31;
      float* dst = ((z == 1) ? Kb : Vb) + (size_t)(b * NH + h) * 8192 + t * DH + d0;
      *(float4*)dst = r;
    }
  }
}

// ---------------- wo GEMM + residual ----------------
__global__ __launch_bounds__(256) void wo_kernel(
    const float* __restrict__ AO, const float* __restrict__ wo, const float* __restrict__ bo,
    const float* __restrict__ srcin, float* __restrict__ X)
{
  int m0 = blockIdx.y * 64, n0 = blockIdx.x * 64;
  float acc[4][4] = {};
  gemm_core(AO, DMODEL, wo, DMODEL, 0, DMODEL, m0, n0, acc);
  int tid = threadIdx.x, tx = tid & 15, ty = tid >> 4;
  int c0 = n0 + tx * 4;
#pragma unroll
  for (int i = 0; i < 4; ++i) {
    int m = m0 + ty * 4 + i;
    float4 rs = *(const float4*)&srcin[m * DMODEL + c0];
    float4 r;
    r.x = acc[i][0] + bo[c0 + 0] + rs.x;
    r.y = acc[i][1] + bo[c0 + 1] + rs.y;
    r.z = acc[i][2] + bo[c0 + 2] + rs.z;
    r.w = acc[i][3] + bo[c0 + 3] + rs.w;
    *(float4*)&X[m * DMODEL + c0] = r;
  }
}

// ---------------- FF1 GEMM + ReLU ----------------
__global__ __launch_bounds__(256) void ff1_kernel(
    const float* __restrict__ XN, const float* __restrict__ w1, const float* __restrict__ b1,
    float* __restrict__ H1)
{
  int m0 = blockIdx.y * 64, n0 = blockIdx.x * 64;
  float acc[4][4] = {};
  gemm_core(XN, DMODEL, w1, 1024, 0, DMODEL, m0, n0, acc);
  int tid = threadIdx.x, tx = tid & 15, ty = tid >> 4;
  int c0 = n0 + tx * 4;
#pragma unroll
  for (int i = 0; i < 4; ++i) {
    int m = m0 + ty * 4 + i;
    float4 r;
    r.x = fmaxf(acc[i][0] + b1[c0 + 0], 0.0f);
    r.y = fmaxf(acc[i][1] + b1[c0 + 1], 0.0f);
    r.z = fmaxf(acc[i][2] + b1[c0 + 2], 0.0f);
    r.w = fmaxf(acc[i][3] + b1[c0 + 3], 0.0f);
    *(float4*)&H1[m * 1024 + c0] = r;
  }
}

// ---------------- FF2 split-K GEMM, masked atomic accumulate ----------------
__global__ __launch_bounds__(256) void ff2_kernel(
    const float* __restrict__ H1, const float* __restrict__ w2,
    const int* __restrict__ smask, float* __restrict__ outb)
{
  int m0 = blockIdx.y * 64, n0 = blockIdx.x * 64;
  int kbeg = blockIdx.z * 256;
  float acc[4][4] = {};
  gemm_core(H1, 1024, w2, DMODEL, kbeg, kbeg + 256, m0, n0, acc);
  int tid = threadIdx.x, tx = tid & 15, ty = tid >> 4;
  int c0 = n0 + tx * 4;
#pragma unroll
  for (int i = 0; i < 4; ++i) {
    int m = m0 + ty * 4 + i;
    float mm = (smask[m] != 0) ? 0.0f : 1.0f;
    atomicAdd(&outb[m * DMODEL + c0 + 0], mm * acc[i][0]);
    atomicAdd(&outb[m * DMODEL + c0 + 1], mm * acc[i][1]);
    atomicAdd(&outb[m * DMODEL + c0 + 2], mm * acc[i][2]);
    atomicAdd(&outb[m * DMODEL + c0 + 3], mm * acc[i][3]);
  }
}

// ---------------- attention: 1 wave per (b,h,s); rank-4 RPE factorization ----------------
__global__ __launch_bounds__(64) void attn_kernel(
    const float* __restrict__ Qb, const float* __restrict__ Kb, const float* __restrict__ Vb,
    const float* __restrict__ rpe, const int* __restrict__ tmask,
    const float* __restrict__ wrl, const float* __restrict__ brl,
    float* __restrict__ AO)
{
  __shared__ float qs[DH];
  __shared__ float red[64 * 33];
  int bid = blockIdx.x;
  int s = bid & 255, h = (bid >> 8) & 7, b = bid >> 11;
  int lane = threadIdx.x;
  if (lane < DH) qs[lane] = Qb[(b * 256 + s) * DMODEL + h * DH + lane];
  __syncthreads();
  float qreg[DH];
#pragma unroll
  for (int d = 0; d < DH; ++d) qreg[d] = qs[d];
  // qwr_j = q . wr_k[j, h, :]   (q already prescaled by 1/sqrt(Dh))
  float qw0 = 0, qw1 = 0, qw2 = 0, qw3 = 0, qbr = 0;
  const float* wrh = wrl + h * DH;
#pragma unroll
  for (int d = 0; d < DH; ++d) {
    float qd = qreg[d];
    qw0 = fmaf(qd, wrh[d],        qw0);
    qw1 = fmaf(qd, wrh[512 + d],  qw1);
    qw2 = fmaf(qd, wrh[1024 + d], qw2);
    qw3 = fmaf(qd, wrh[1536 + d], qw3);
    qbr = fmaf(qd, brl[h * DH + d], qbr);
  }
  const float*  Kp  = Kb + (size_t)(b * NH + h) * 8192;
  const float*  Vp  = Vb + (size_t)(b * NH + h) * 8192;
  const float4* rp4 = (const float4*)(rpe + ((size_t)(b * 256 + s) * 256) * 4);
  float sc[4]; float4 rp[4];
#pragma unroll
  for (int i = 0; i < 4; ++i) {
    int t = i * 64 + lane;
    const float4* kv = (const float4*)(Kp + t * DH);
    float sv = 0;
#pragma unroll
    for (int c = 0; c < 8; ++c) {
      float4 k4 = kv[c];
      sv = fmaf(qreg[c*4+0], k4.x, sv);
      sv = fmaf(qreg[c*4+1], k4.y, sv);
      sv = fmaf(qreg[c*4+2], k4.z, sv);
      sv = fmaf(qreg[c*4+3], k4.w, sv);
    }
    float4 rr = rp4[t];
    rp[i] = rr;
    sv += rr.x*qw0 + rr.y*qw1 + rr.z*qw2 + rr.w*qw3 + qbr;
    if (tmask[b * 256 + t] != 0) sv = NEG_INF;
    sc[i] = sv;
  }
  float mval = fmaxf(fmaxf(sc[0], sc[1]), fmaxf(sc[2], sc[3]));
#pragma unroll
  for (int off = 32; off >= 1; off >>= 1) mval = fmaxf(mval, __shfl_xor(mval, off));
  float p[4], lsum = 0;
#pragma unroll
  for (int i = 0; i < 4; ++i) { p[i] = __expf(sc[i] - mval); lsum += p[i]; }
#pragma unroll
  for (int off = 32; off >= 1; off >>= 1) lsum += __shfl_xor(lsum, off);
  // PV accumulation + wrpe_j = sum_t w_t * rpe_j (unnormalized; divide by lsum at end)
  float acc[DH];
#pragma unroll
  for (int d = 0; d < DH; ++d) acc[d] = 0.0f;
  float wj0 = 0, wj1 = 0, wj2 = 0, wj3 = 0;
#pragma unroll
  for (int i = 0; i < 4; ++i) {
    int t = i * 64 + lane;
    float wgt = p[i];
    const float4* vv = (const float4*)(Vp + t * DH);
#pragma unroll
    for (int c = 0; c < 8; ++c) {
      float4 v4 = vv[c];
      acc[c*4+0] = fmaf(wgt, v4.x, acc[c*4+0]);
      acc[c*4+1] = fmaf(wgt, v4.y, acc[c*4+1]);
      acc[c*4+2] = fmaf(wgt, v4.z, acc[c*4+2]);
      acc[c*4+3] = fmaf(wgt, v4.w, acc[c*4+3]);
    }
    wj0 = fmaf(wgt, rp[i].x, wj0);
    wj1 = fmaf(wgt, rp[i].y, wj1);
    wj2 = fmaf(wgt, rp[i].z, wj2);
    wj3 = fmaf(wgt, rp[i].w, wj3);
  }
#pragma unroll
  for (int off = 32; off >= 1; off >>= 1) {
    wj0 += __shfl_xor(wj0, off);
    wj1 += __shfl_xor(wj1, off);
    wj2 += __shfl_xor(wj2, off);
    wj3 += __shfl_xor(wj3, off);
  }
#pragma unroll
  for (int d = 0; d < DH; ++d) red[lane * 33 + d] = acc[d];
  __syncthreads();
  int col = lane & 31, half = lane >> 5;
  float o = 0;
#pragma unroll
  for (int i = 0; i < 32; ++i) o += red[(half * 32 + i) * 33 + col];
  o += __shfl_xor(o, 32);
  if (lane < DH) {
    int d = lane;
    const float* wrv = wrl + 256 + h * DH + d;  // v-half of wr rows
    float corr = wj0 * wrv[0] + wj1 * wrv[512] + wj2 * wrv[1024] + wj3 * wrv[1536];
    float oval = (o + corr) / lsum + brl[256 + h * DH + d];
    AO[(b * 256 + s) * DMODEL + h * DH + d] = oval;
  }
}

extern "C" void kernel_launch(void* const* d_in, const int* in_sizes, int n_in,
                              void* d_out, int out_size, void* d_ws, size_t ws_size,
                              hipStream_t stream)
{
  const float* src  = (const float*)d_in[0];
  const float* tgt  = (const float*)d_in[1];
  const float* rpe  = (const float*)d_in[2];
  const int*   smask = (const int*)d_in[3];
  const int*   tmask = (const int*)d_in[4];
  const float* ln1g = (const float*)d_in[5];
  const float* ln1b = (const float*)d_in[6];
  const float* lntg = (const float*)d_in[7];
  const float* lntb = (const float*)d_in[8];
  const float* ln2g = (const float*)d_in[9];
  const float* ln2b = (const float*)d_in[10];
  const float* wq = (const float*)d_in[11];
  const float* bq = (const float*)d_in[12];
  const float* wk = (const float*)d_in[13];
  const float* bk = (const float*)d_in[14];
  const float* wv = (const float*)d_in[15];
  const float* bv = (const float*)d_in[16];
  const float* wo = (const float*)d_in[17];
  const float* bo = (const float*)d_in[18];
  const float* wr = (const float*)d_in[19];
  const float* br = (const float*)d_in[20];
  const float* w1 = (const float*)d_in[21];
  const float* b1 = (const float*)d_in[22];
  const float* w2 = (const float*)d_in[23];
  const float* b2 = (const float*)d_in[24];

  float* w    = (float*)d_ws;
  float* S2   = w;
  float* TNb  = w + 131072;
  float* Qb   = w + 262144;
  float* Kb   = w + 393216;
  float* Vb   = w + 524288;
  float* AO   = w + 655360;
  float* X    = w + 786432;
  float* XN   = w + 917504;
  float* SRC1 = w + 1048576;
  float* H1   = w + 1179648;   // 524288 floats; total ws use ~6.8 MB

  for (int l = 0; l < 2; ++l) {
    const float* srcin = l ? SRC1 : src;
    float* outb = l ? (float*)d_out : SRC1;
    ln_qt_kernel<<<1024, 64, 0, stream>>>(srcin, tgt, ln1g + l*256, ln1b + l*256,
                                          lntg + l*256, lntb + l*256, S2, TNb);
    qkv_kernel<<<dim3(4, 8, 3), 256, 0, stream>>>(S2, TNb,
                                                  wq + l*65536, wk + l*65536, wv + l*65536,
                                                  bq + l*256, bk + l*256, bv + l*256,
                                                  Qb, Kb, Vb);
    attn_kernel<<<4096, 64, 0, stream>>>(Qb, Kb, Vb, rpe, tmask,
                                         wr + l*2048, br + l*512, AO);
    wo_kernel<<<dim3(4, 8), 256, 0, stream>>>(AO, wo + l*65536, bo + l*256, srcin, X);
    ln2_kernel<<<512, 64, 0, stream>>>(X, ln2g + l*256, ln2b + l*256, b2 + l*256,
                                       smask, XN, outb);
    ff1_kernel<<<dim3(16, 8), 256, 0, stream>>>(XN, w1 + l*262144, b1 + l*1024, H1);
    ff2_kernel<<<dim3(4, 8, 4), 256, 0, stream>>>(H1, w2 + l*262144, smask, outb);
  }
}

// Round 3
// 262.838 us; speedup vs baseline: 1.4382x; 1.4382x over previous
//
#include <hip/hip_runtime.h>
#include <math.h>

#define ROWS 512       // B*S = B*T
#define DMODEL 256
#define NH 8
#define DH 32
#define NEG_INF -1e30f

// ---------- LayerNorm over src (ln1) and tgt (lnt); also X := src + bo ----------
__global__ __launch_bounds__(64) void ln_qt_kernel(
    const float* __restrict__ src, const float* __restrict__ tgt,
    const float* __restrict__ g1, const float* __restrict__ b1,
    const float* __restrict__ gt, const float* __restrict__ bt,
    const float* __restrict__ bo,
    float* __restrict__ S2, float* __restrict__ TNb, float* __restrict__ X)
{
  int row = blockIdx.x;           // 0..1023
  const float* x; float* o; const float* g; const float* b;
  if (row < ROWS) { x = src + row * DMODEL; o = S2 + row * DMODEL; g = g1; b = b1; }
  else { int r = row - ROWS; x = tgt + r * DMODEL; o = TNb + r * DMODEL; g = gt; b = bt; }
  int lane = threadIdx.x;
  float4 v = ((const float4*)x)[lane];
  float s  = v.x + v.y + v.z + v.w;
  float ss = v.x*v.x + v.y*v.y + v.z*v.z + v.w*v.w;
#pragma unroll
  for (int off = 32; off >= 1; off >>= 1) {
    s  += __shfl_xor(s,  off);
    ss += __shfl_xor(ss, off);
  }
  float mean = s * (1.0f / 256.0f);
  float var  = ss * (1.0f / 256.0f) - mean * mean;
  float rstd = rsqrtf(var + 1e-5f);
  float4 gg = ((const float4*)g)[lane];
  float4 bb = ((const float4*)b)[lane];
  float4 ov;
  ov.x = (v.x - mean) * rstd * gg.x + bb.x;
  ov.y = (v.y - mean) * rstd * gg.y + bb.y;
  ov.z = (v.z - mean) * rstd * gg.z + bb.z;
  ov.w = (v.w - mean) * rstd * gg.w + bb.w;
  ((float4*)o)[lane] = ov;
  if (row < ROWS) {   // X init for wo split-K accumulate: src + bo
    float4 bov = ((const float4*)bo)[lane];
    float4 xi;
    xi.x = v.x + bov.x; xi.y = v.y + bov.y; xi.z = v.z + bov.z; xi.w = v.w + bov.w;
    ((float4*)(X + row * DMODEL))[lane] = xi;
  }
}

// ---------- LN2 + FF2-output init (residual + b2, masked) ----------
__global__ __launch_bounds__(64) void ln2_kernel(
    const float* __restrict__ X, const float* __restrict__ g, const float* __restrict__ b,
    const float* __restrict__ b2, const int* __restrict__ smask,
    float* __restrict__ XN, float* __restrict__ outinit)
{
  int row = blockIdx.x;           // 0..511
  int lane = threadIdx.x;
  float4 v = ((const float4*)(X + row * DMODEL))[lane];
  float s  = v.x + v.y + v.z + v.w;
  float ss = v.x*v.x + v.y*v.y + v.z*v.z + v.w*v.w;
#pragma unroll
  for (int off = 32; off >= 1; off >>= 1) {
    s  += __shfl_xor(s,  off);
    ss += __shfl_xor(ss, off);
  }
  float mean = s * (1.0f / 256.0f);
  float var  = ss * (1.0f / 256.0f) - mean * mean;
  float rstd = rsqrtf(var + 1e-5f);
  float4 gg = ((const float4*)g)[lane];
  float4 bb = ((const float4*)b)[lane];
  float4 ov;
  ov.x = (v.x - mean) * rstd * gg.x + bb.x;
  ov.y = (v.y - mean) * rstd * gg.y + bb.y;
  ov.z = (v.z - mean) * rstd * gg.z + bb.z;
  ov.w = (v.w - mean) * rstd * gg.w + bb.w;
  ((float4*)(XN + row * DMODEL))[lane] = ov;
  float mm = (smask[row] != 0) ? 0.0f : 1.0f;
  float4 b2v = ((const float4*)b2)[lane];
  float4 oi;
  oi.x = mm * (v.x + b2v.x);
  oi.y = mm * (v.y + b2v.y);
  oi.z = mm * (v.z + b2v.z);
  oi.w = mm * (v.w + b2v.w);
  ((float4*)(outinit + row * DMODEL))[lane] = oi;
}

// ---------- GEMM core: 32x64 tile, 2x4 micro, 256 thr, KC=32 ----------
__device__ __forceinline__ void gemm_core32(
    const float* __restrict__ A, int lda,
    const float* __restrict__ Bw, int ldb,
    int kbeg, int kend, int m0, int n0,
    float acc[2][4])
{
  __shared__ float At[32][34];   // [k][m], pad 34 keeps b64 8B-aligned, banks 0,2,4,6
  __shared__ float Bs[32][64];
  int tid = threadIdx.x;
  int tx = tid & 15, ty = tid >> 4;
  int r  = tid >> 3;             // 0..31 : A row / B k-row
  int c4 = tid & 7;              // chunk
  for (int kc = kbeg; kc < kend; kc += 32) {
    float4 a = *(const float4*)(A + (size_t)(m0 + r) * lda + kc + c4 * 4);
    const float* bp = Bw + (size_t)(kc + r) * ldb + n0;
    float4 b0 = *(const float4*)(bp + c4 * 4);
    float4 b1v = *(const float4*)(bp + 32 + c4 * 4);
    At[c4*4+0][r] = a.x; At[c4*4+1][r] = a.y; At[c4*4+2][r] = a.z; At[c4*4+3][r] = a.w;
    *(float4*)&Bs[r][c4*4]      = b0;
    *(float4*)&Bs[r][32 + c4*4] = b1v;
    __syncthreads();
#pragma unroll
    for (int k = 0; k < 32; ++k) {
      float2 av = *(const float2*)&At[k][ty * 2];
      float4 bv = *(const float4*)&Bs[k][tx * 4];
      acc[0][0] = fmaf(av.x, bv.x, acc[0][0]); acc[0][1] = fmaf(av.x, bv.y, acc[0][1]);
      acc[0][2] = fmaf(av.x, bv.z, acc[0][2]); acc[0][3] = fmaf(av.x, bv.w, acc[0][3]);
      acc[1][0] = fmaf(av.y, bv.x, acc[1][0]); acc[1][1] = fmaf(av.y, bv.y, acc[1][1]);
      acc[1][2] = fmaf(av.y, bv.z, acc[1][2]); acc[1][3] = fmaf(av.y, bv.w, acc[1][3]);
    }
    __syncthreads();
  }
}

// ---------- QKV: grid (4,16,3); Q prescaled; K/V stored [B,H,T,Dh] ----------
__global__ __launch_bounds__(256) void qkv_kernel(
    const float* __restrict__ S2, const float* __restrict__ TNb,
    const float* __restrict__ wq, const float* __restrict__ wk, const float* __restrict__ wv,
    const float* __restrict__ bq, const float* __restrict__ bk, const float* __restrict__ bv,
    float* __restrict__ Qb, float* __restrict__ Kb, float* __restrict__ Vb)
{
  int z = blockIdx.z;
  const float* A    = (z == 0) ? S2 : TNb;
  const float* Bw   = (z == 0) ? wq : (z == 1) ? wk : wv;
  const float* bias = (z == 0) ? bq : (z == 1) ? bk : bv;
  int m0 = blockIdx.y * 32, n0 = blockIdx.x * 64;
  float acc[2][4] = {};
  gemm_core32(A, DMODEL, Bw, DMODEL, 0, DMODEL, m0, n0, acc);
  int tid = threadIdx.x, tx = tid & 15, ty = tid >> 4;
  int c0 = n0 + tx * 4;
  const float scale = 0.1767766952966369f; // 1/sqrt(32)
#pragma unroll
  for (int i = 0; i < 2; ++i) {
    int m = m0 + ty * 2 + i;
    float4 r;
    r.x = acc[i][0] + bias[c0 + 0];
    r.y = acc[i][1] + bias[c0 + 1];
    r.z = acc[i][2] + bias[c0 + 2];
    r.w = acc[i][3] + bias[c0 + 3];
    if (z == 0) {
      r.x *= scale; r.y *= scale; r.z *= scale; r.w *= scale;
      *(float4*)&Qb[m * DMODEL + c0] = r;
    } else {
      int b = m >> 8, t = m & 255, h = c0 >> 5, d0 = c0 & 31;
      float* dst = ((z == 1) ? Kb : Vb) + (size_t)(b * NH + h) * 8192 + t * DH + d0;
      *(float4*)dst = r;
    }
  }
}

// ---------- wo GEMM split-K=2, atomic into X (pre-init src+bo) ----------
__global__ __launch_bounds__(256) void wo_kernel(
    const float* __restrict__ AO, const float* __restrict__ wo,
    float* __restrict__ X)
{
  int m0 = blockIdx.y * 32, n0 = blockIdx.x * 64;
  int kbeg = blockIdx.z * 128;
  float acc[2][4] = {};
  gemm_core32(AO, DMODEL, wo, DMODEL, kbeg, kbeg + 128, m0, n0, acc);
  int tid = threadIdx.x, tx = tid & 15, ty = tid >> 4;
  int c0 = n0 + tx * 4;
#pragma unroll
  for (int i = 0; i < 2; ++i) {
    int m = m0 + ty * 2 + i;
    atomicAdd(&X[m * DMODEL + c0 + 0], acc[i][0]);
    atomicAdd(&X[m * DMODEL + c0 + 1], acc[i][1]);
    atomicAdd(&X[m * DMODEL + c0 + 2], acc[i][2]);
    atomicAdd(&X[m * DMODEL + c0 + 3], acc[i][3]);
  }
}

// ---------- FF1 GEMM + ReLU : grid (16,16) ----------
__global__ __launch_bounds__(256) void ff1_kernel(
    const float* __restrict__ XN, const float* __restrict__ w1, const float* __restrict__ b1,
    float* __restrict__ H1)
{
  int m0 = blockIdx.y * 32, n0 = blockIdx.x * 64;
  float acc[2][4] = {};
  gemm_core32(XN, DMODEL, w1, 1024, 0, DMODEL, m0, n0, acc);
  int tid = threadIdx.x, tx = tid & 15, ty = tid >> 4;
  int c0 = n0 + tx * 4;
#pragma unroll
  for (int i = 0; i < 2; ++i) {
    int m = m0 + ty * 2 + i;
    float4 r;
    r.x = fmaxf(acc[i][0] + b1[c0 + 0], 0.0f);
    r.y = fmaxf(acc[i][1] + b1[c0 + 1], 0.0f);
    r.z = fmaxf(acc[i][2] + b1[c0 + 2], 0.0f);
    r.w = fmaxf(acc[i][3] + b1[c0 + 3], 0.0f);
    *(float4*)&H1[m * 1024 + c0] = r;
  }
}

// ---------- FF2 split-K=4 GEMM, masked atomic accumulate : grid (4,16,4) ----------
__global__ __launch_bounds__(256) void ff2_kernel(
    const float* __restrict__ H1, const float* __restrict__ w2,
    const int* __restrict__ smask, float* __restrict__ outb)
{
  int m0 = blockIdx.y * 32, n0 = blockIdx.x * 64;
  int kbeg = blockIdx.z * 256;
  float acc[2][4] = {};
  gemm_core32(H1, 1024, w2, DMODEL, kbeg, kbeg + 256, m0, n0, acc);
  int tid = threadIdx.x, tx = tid & 15, ty = tid >> 4;
  int c0 = n0 + tx * 4;
#pragma unroll
  for (int i = 0; i < 2; ++i) {
    int m = m0 + ty * 2 + i;
    float mm = (smask[m] != 0) ? 0.0f : 1.0f;
    atomicAdd(&outb[m * DMODEL + c0 + 0], mm * acc[i][0]);
    atomicAdd(&outb[m * DMODEL + c0 + 1], mm * acc[i][1]);
    atomicAdd(&outb[m * DMODEL + c0 + 2], mm * acc[i][2]);
    atomicAdd(&outb[m * DMODEL + c0 + 3], mm * acc[i][3]);
  }
}

// ---------- attention: block = (b,h,16 s-rows), 256 thr; K/V in LDS ----------
__global__ __launch_bounds__(256) void attn_kernel(
    const float* __restrict__ Qb, const float* __restrict__ Kb, const float* __restrict__ Vb,
    const float* __restrict__ rpe, const int* __restrict__ tmask,
    const float* __restrict__ wrl, const float* __restrict__ brl,
    float* __restrict__ AO)
{
  __shared__ float Ks[256][32];
  __shared__ float Vt[32][260];
  __shared__ float ps[4][256];
  __shared__ float qs[16][32];
  __shared__ float wks[5][32];   // wr_k rows j=0..3, row4 = br_k  (for head h)
  __shared__ float wvs[5][32];   // wr_v rows j=0..3, row4 = br_v
  int bid = blockIdx.x;
  int b = bid >> 7, h = (bid >> 4) & 7, s0 = (bid & 15) << 4;
  int tid = threadIdx.x;
  const float* Kp = Kb + (size_t)(b * NH + h) * 8192;
  const float* Vp = Vb + (size_t)(b * NH + h) * 8192;
  {
    int t = tid;
    const float4* kr = (const float4*)(Kp + t * DH);
    const float4* vr = (const float4*)(Vp + t * DH);
    int sw = t & 7;
#pragma unroll
    for (int c = 0; c < 8; ++c) {
      float4 k4 = kr[c];
      *(float4*)&Ks[t][(c ^ sw) * 4] = k4;
    }
#pragma unroll
    for (int c = 0; c < 8; ++c) {
      float4 v4 = vr[c];
      Vt[c*4+0][t] = v4.x; Vt[c*4+1][t] = v4.y; Vt[c*4+2][t] = v4.z; Vt[c*4+3][t] = v4.w;
    }
  }
  if (tid < 160) {               // FIX: 160 threads cover j=0..4 (was tid>=128, capped at j<4)
    int j = tid >> 5, d = tid & 31;
    wks[j][d] = (j < 4) ? wrl[j * 512 + h * DH + d]       : brl[h * DH + d];
    wvs[j][d] = (j < 4) ? wrl[j * 512 + 256 + h * DH + d] : brl[256 + h * DH + d];
  }
  if (tid >= 128) {              // 128 threads load the 16x32 Q tile
    int u = tid - 128;
    int rr = u >> 3, cc = u & 7;
    *(float4*)&qs[rr][cc*4] =
        *(const float4*)&Qb[(b * 256 + s0 + rr) * DMODEL + h * DH + cc * 4];
  }
  __syncthreads();

  int w = tid >> 6, lane = tid & 63;
  int msk[4];
#pragma unroll
  for (int it = 0; it < 4; ++it) msk[it] = tmask[b * 256 + it * 64 + lane];

  for (int i = 0; i < 4; ++i) {
    int sl = w * 4 + i;
    int s = s0 + sl;
    float4 q4[8];
#pragma unroll
    for (int c = 0; c < 8; ++c) q4[c] = *(const float4*)&qs[sl][c * 4];
    float qw[4]; float qbr = 0.0f;
#pragma unroll
    for (int j = 0; j < 4; ++j) {
      float t0 = 0;
#pragma unroll
      for (int c = 0; c < 8; ++c) {
        float4 wv4 = *(const float4*)&wks[j][c * 4];
        t0 += q4[c].x*wv4.x + q4[c].y*wv4.y + q4[c].z*wv4.z + q4[c].w*wv4.w;
      }
      qw[j] = t0;
    }
#pragma unroll
    for (int c = 0; c < 8; ++c) {
      float4 wv4 = *(const float4*)&wks[4][c * 4];
      qbr += q4[c].x*wv4.x + q4[c].y*wv4.y + q4[c].z*wv4.z + q4[c].w*wv4.w;
    }
    const float4* rp4 = (const float4*)(rpe + (size_t)(b * 256 + s) * 1024);
    float sc[4]; float4 rr[4];
#pragma unroll
    for (int it = 0; it < 4; ++it) {
      int t = it * 64 + lane;
      int sw = t & 7;
      float sv = 0;
#pragma unroll
      for (int c = 0; c < 8; ++c) {
        float4 k4 = *(const float4*)&Ks[t][(c ^ sw) * 4];
        sv = fmaf(q4[c].x, k4.x, sv); sv = fmaf(q4[c].y, k4.y, sv);
        sv = fmaf(q4[c].z, k4.z, sv); sv = fmaf(q4[c].w, k4.w, sv);
      }
      float4 rv = rp4[t];
      rr[it] = rv;
      sv += rv.x*qw[0] + rv.y*qw[1] + rv.z*qw[2] + rv.w*qw[3] + qbr;
      if (msk[it] != 0) sv = NEG_INF;
      sc[it] = sv;
    }
    float mval = fmaxf(fmaxf(sc[0], sc[1]), fmaxf(sc[2], sc[3]));
#pragma unroll
    for (int off = 32; off >= 1; off >>= 1) mval = fmaxf(mval, __shfl_xor(mval, off));
    float p[4], lsum = 0;
#pragma unroll
    for (int it = 0; it < 4; ++it) { p[it] = __expf(sc[it] - mval); lsum += p[it]; }
    float wj0 = 0, wj1 = 0, wj2 = 0, wj3 = 0;
#pragma unroll
    for (int it = 0; it < 4; ++it) {
      wj0 = fmaf(p[it], rr[it].x, wj0);
      wj1 = fmaf(p[it], rr[it].y, wj1);
      wj2 = fmaf(p[it], rr[it].z, wj2);
      wj3 = fmaf(p[it], rr[it].w, wj3);
    }
#pragma unroll
    for (int off = 32; off >= 1; off >>= 1) {
      lsum += __shfl_xor(lsum, off);
      wj0 += __shfl_xor(wj0, off);
      wj1 += __shfl_xor(wj1, off);
      wj2 += __shfl_xor(wj2, off);
      wj3 += __shfl_xor(wj3, off);
    }
#pragma unroll
    for (int it = 0; it < 4; ++it) ps[w][it * 64 + lane] = p[it];
    // PV: lane (g,d) accumulates o[d] over its t-half from LDS
    int g = lane >> 5, d = lane & 31;
    float o = 0;
#pragma unroll
    for (int n = 0; n < 32; ++n) {
      int t = g * 128 + n * 4;
      float4 p4 = *(const float4*)&ps[w][t];
      float4 v4 = *(const float4*)&Vt[d][t];
      o += p4.x*v4.x + p4.y*v4.y + p4.z*v4.z + p4.w*v4.w;
    }
    o += __shfl_xor(o, 32);
    float corr = wj0 * wvs[0][d] + wj1 * wvs[1][d] + wj2 * wvs[2][d] + wj3 * wvs[3][d];
    float oval = (o + corr) / lsum + wvs[4][d];
    if (lane < 32) AO[(b * 256 + s) * DMODEL + h * DH + d] = oval;
  }
}

extern "C" void kernel_launch(void* const* d_in, const int* in_sizes, int n_in,
                              void* d_out, int out_size, void* d_ws, size_t ws_size,
                              hipStream_t stream)
{
  const float* src  = (const float*)d_in[0];
  const float* tgt  = (const float*)d_in[1];
  const float* rpe  = (const float*)d_in[2];
  const int*   smask = (const int*)d_in[3];
  const int*   tmask = (const int*)d_in[4];
  const float* ln1g = (const float*)d_in[5];
  const float* ln1b = (const float*)d_in[6];
  const float* lntg = (const float*)d_in[7];
  const float* lntb = (const float*)d_in[8];
  const float* ln2g = (const float*)d_in[9];
  const float* ln2b = (const float*)d_in[10];
  const float* wq = (const float*)d_in[11];
  const float* bq = (const float*)d_in[12];
  const float* wk = (const float*)d_in[13];
  const float* bk = (const float*)d_in[14];
  const float* wv = (const float*)d_in[15];
  const float* bv = (const float*)d_in[16];
  const float* wo = (const float*)d_in[17];
  const float* bo = (const float*)d_in[18];
  const float* wr = (const float*)d_in[19];
  const float* br = (const float*)d_in[20];
  const float* w1 = (const float*)d_in[21];
  const float* b1 = (const float*)d_in[22];
  const float* w2 = (const float*)d_in[23];
  const float* b2 = (const float*)d_in[24];

  float* w    = (float*)d_ws;
  float* S2   = w;
  float* TNb  = w + 131072;
  float* Qb   = w + 262144;
  float* Kb   = w + 393216;
  float* Vb   = w + 524288;
  float* AO   = w + 655360;
  float* X    = w + 786432;
  float* XN   = w + 917504;
  float* SRC1 = w + 1048576;
  float* H1   = w + 1179648;

  for (int l = 0; l < 2; ++l) {
    const float* srcin = l ? SRC1 : src;
    float* outb = l ? (float*)d_out : SRC1;
    ln_qt_kernel<<<1024, 64, 0, stream>>>(srcin, tgt, ln1g + l*256, ln1b + l*256,
                                          lntg + l*256, lntb + l*256, bo + l*256,
                                          S2, TNb, X);
    qkv_kernel<<<dim3(4, 16, 3), 256, 0, stream>>>(S2, TNb,
                                                   wq + l*65536, wk + l*65536, wv + l*65536,
                                                   bq + l*256, bk + l*256, bv + l*256,
                                                   Qb, Kb, Vb);
    attn_kernel<<<256, 256, 0, stream>>>(Qb, Kb, Vb, rpe, tmask,
                                         wr + l*2048, br + l*512, AO);
    wo_kernel<<<dim3(4, 16, 2), 256, 0, stream>>>(AO, wo + l*65536, X);
    ln2_kernel<<<512, 64, 0, stream>>>(X, ln2g + l*256, ln2b + l*256, b2 + l*256,
                                       smask, XN, outb);
    ff1_kernel<<<dim3(16, 16), 256, 0, stream>>>(XN, w1 + l*262144, b1 + l*1024, H1);
    ff2_kernel<<<dim3(4, 16, 4), 256, 0, stream>>>(H1, w2 + l*262144, smask, outb);
  }
}